// Round 9
// baseline (270.320 us; speedup 1.0000x reference)
//
#include <hip/hip_runtime.h>
#include <stdint.h>

typedef unsigned short u16;
typedef __attribute__((ext_vector_type(8))) short bf16x8;   // 8 bf16 = 4 VGPRs
typedef __attribute__((ext_vector_type(4))) float f32x4;

#define MFMA16(a, b, c) __builtin_amdgcn_mfma_f32_16x16x32_bf16((a), (b), (c), 0, 0, 0)

__device__ __forceinline__ u16 f2b(float f) {   // fp32 -> bf16 RNE
  uint32_t u = __float_as_uint(f);
  u += 0x7FFFu + ((u >> 16) & 1u);
  return (u16)(u >> 16);
}
__device__ __forceinline__ float tanhfast(float x) {
  float e = __expf(2.f * x);
  return (e - 1.f) / (e + 1.f);
}

// ---------------- workspace layout (bytes) ----------------
// region0: h1 bf16 [8192][12][12][16]  @ 0         37,748,736
//          e1b bf16 [8192][640] overlays region0 (h1 dead after conv2)
// feat FRAG [128 mt][100 s][4 rb][64 l][8]  @ 37748736  52,428,800
// W1T FRAG [5 e][100 s][8 nb][64 l][8]      @ 90177536   4,096,000
// W2T bf16 [5][128][128]            @ 94273536      163,840
// W2colF bf16 [5][2][64][8]         @ 94437376       10,240
// WcatT FRAG [100 s][64 l][8]       @ 94447616      102,400
// rw f32 [8192][5]                  @ 94550016      163,840   (total 94.7 MB)

// ============ prep_misc: small weight repacks ============
__global__ __launch_bounds__(256) void prep_misc_kernel(
    const float* __restrict__ c2w, const float* __restrict__ Wg,
    const float* __restrict__ Wglu, const float* __restrict__ W2e,
    u16* __restrict__ W2colF, u16* __restrict__ WcatT, u16* __restrict__ W2T) {
  int i = blockIdx.x * 256 + threadIdx.x;
  if (i < 5120) {                       // conv2 B-fragments, k=(ky*3+kx)*16+ci, pad->160
    int j = i & 7, l = (i >> 3) & 63, nt = (i >> 9) & 1, s = i >> 10;
    int k = s * 32 + ((l >> 4) & 3) * 8 + j;
    int n = (l & 15) + nt * 16;
    float v = 0.f;
    if (k < 144) {
      int kykx = k >> 4, ci = k & 15;
      int ky = kykx / 3, kx = kykx - ky * 3;
      v = c2w[((n * 16 + ci) * 3 + ky) * 3 + kx];
    }
    W2colF[i] = f2b(v);
  } else if (i < 56320) {               // WcatT FRAG [s][l][8]
    int o = i - 5120;
    int s = o >> 9, rest = o & 511;
    int l = rest >> 3, j = rest & 7;
    int r = l & 15, c = (l >> 4) * 8 + j;
    int dref = c * 100 + s;
    float v = 0.f;
    if (r < 5) v = Wg[dref * 5 + r];
    else if (r < 10) v = Wglu[dref * 5 + (r - 5)];
    WcatT[o] = f2b(v);
  } else if (i < 138240) {              // W2T[e][g][h]
    int o = i - 56320;
    int e = o >> 14, rem = o & 16383;
    int g = rem >> 7, h = rem & 127;
    W2T[o] = f2b(W2e[(e * 128 + h) * 128 + g]);
  }
}

// ============ prep_w1t: W1e[e][d][n] -> W1T FRAG [e][s][nb][l][8] ============
__global__ __launch_bounds__(256) void prep_w1t_kernel(
    const float* __restrict__ W1e, u16* __restrict__ W1T) {
  __shared__ u16 ts[64][128];           // [ph*32+c][n]
  int t = threadIdx.x;
  int e = blockIdx.x / 50, pt = blockIdx.x % 50;   // 2 p-values per block
  {
    int r64 = t >> 2;                   // 0..63: ph = r64>>5, c = r64&31
    int ph = r64 >> 5, c = r64 & 31;
    int d = c * 100 + pt * 2 + ph;
    const float* src = W1e + ((size_t)e * 3200 + d) * 128 + (t & 3) * 32;
    u16* drow = &ts[r64][(t & 3) * 32];
#pragma unroll
    for (int u = 0; u < 8; u++) {
      float4 v = *(const float4*)(src + u * 4);
      drow[u * 4 + 0] = f2b(v.x); drow[u * 4 + 1] = f2b(v.y);
      drow[u * 4 + 2] = f2b(v.z); drow[u * 4 + 3] = f2b(v.w);
    }
  }
  __syncthreads();
#pragma unroll
  for (int k = 0; k < 4; k++) {
    int u = t + k * 256;                // 1024 chunks of 16 B
    int ph = u >> 9, nb = (u >> 6) & 7, l = u & 63;
    int lm = l & 15, lqf = l >> 4;
    u16 tmp[8];
#pragma unroll
    for (int j = 0; j < 8; j++)
      tmp[j] = ts[ph * 32 + lqf * 8 + j][nb * 16 + lm];
    *(uint4*)(W1T + (((size_t)((e * 100 + pt * 2 + ph) * 8 + nb)) << 9) + l * 8) =
        *(const uint4*)tmp;
  }
}

// ============ conv1 MFMA + relu + maxpool2 -> h1 bf16 HWC ============
__global__ __launch_bounds__(256) void conv1_kernel(
    const float* __restrict__ x, const float* __restrict__ w1,
    const float* __restrict__ b1, u16* __restrict__ h1) {
  __shared__ __align__(16) u16 cp[7232];   // [8 copies][28 rows][32], copy stride 904
  int t = threadIdx.x, b = blockIdx.x, w = t >> 6, l = t & 63;

  if (t < 84) {                            // stage shifted copies from registers
    int r = (t * 171) >> 9;                // t/3
    int o = t - r * 3;                     // octet 0..2
    const float4* src = (const float4*)(x + (size_t)b * 784 + r * 28 + o * 8);
    float4 qa = src[0], qb = src[1], qc = src[2];
    float4 qd = {0.f, 0.f, 0.f, 0.f};
    if (o < 2) qd = src[3];
    uint32_t d0 = (uint32_t)f2b(qa.x) | ((uint32_t)f2b(qa.y) << 16);
    uint32_t d1 = (uint32_t)f2b(qa.z) | ((uint32_t)f2b(qa.w) << 16);
    uint32_t d2 = (uint32_t)f2b(qb.x) | ((uint32_t)f2b(qb.y) << 16);
    uint32_t d3 = (uint32_t)f2b(qb.z) | ((uint32_t)f2b(qb.w) << 16);
    uint32_t d4 = (uint32_t)f2b(qc.x) | ((uint32_t)f2b(qc.y) << 16);
    uint32_t d5 = (uint32_t)f2b(qc.z) | ((uint32_t)f2b(qc.w) << 16);
    uint32_t d6 = (uint32_t)f2b(qd.x) | ((uint32_t)f2b(qd.y) << 16);
    uint32_t d7 = (uint32_t)f2b(qd.z) | ((uint32_t)f2b(qd.w) << 16);
#define SH(hi, lo) (((lo) >> 16) | ((hi) << 16))
    int base = r * 32 + o * 8;
    *(uint4*)&cp[base + 0 * 904] = uint4{d0, d1, d2, d3};
    *(uint4*)&cp[base + 1 * 904] = uint4{SH(d1, d0), SH(d2, d1), SH(d3, d2), SH(d4, d3)};
    *(uint4*)&cp[base + 2 * 904] = uint4{d1, d2, d3, d4};
    *(uint4*)&cp[base + 3 * 904] = uint4{SH(d2, d1), SH(d3, d2), SH(d4, d3), SH(d5, d4)};
    *(uint4*)&cp[base + 4 * 904] = uint4{d2, d3, d4, d5};
    *(uint4*)&cp[base + 5 * 904] = uint4{SH(d3, d2), SH(d4, d3), SH(d5, d4), SH(d6, d5)};
    *(uint4*)&cp[base + 6 * 904] = uint4{d3, d4, d5, d6};
    *(uint4*)&cp[base + 7 * 904] = uint4{SH(d4, d3), SH(d5, d4), SH(d6, d5), SH(d7, d6)};
#undef SH
  }

  int lm = l & 15, c = l & 7, ry = (l >> 3) & 1, q = l >> 4;
  bf16x8 bw1 = {0, 0, 0, 0, 0, 0, 0, 0}, bw2 = {0, 0, 0, 0, 0, 0, 0, 0};
#pragma unroll
  for (int j = 0; j < 5; j++) {
    bw1[j] = (short)f2b(w1[lm * 25 + q * 5 + j]);
    if (q == 0) bw2[j] = (short)f2b(w1[lm * 25 + 20 + j]);
  }
  float bias = b1[lm];
  u16* hout = h1 + (size_t)b * 2304;
  __syncthreads();

#pragma unroll
  for (int i = 0; i < 9; i++) {
    int tt = i * 4 + w;                   // 36 tiles: p (y-pair) x xo (x-octet)
    int p = (tt * 171) >> 9;              // tt/3
    int xo = tt - p * 3;
    int r1 = p * 2 + ry + q;              // <= 26
    int r2 = min(r1 + 4, 27);             // clamp: rows >27 have zero weights
    bf16x8 a1 = *(const bf16x8*)&cp[c * 904 + r1 * 32 + xo * 8];
    bf16x8 a2 = *(const bf16x8*)&cp[c * 904 + r2 * 32 + xo * 8];
    f32x4 acc = {0.f, 0.f, 0.f, 0.f};
    acc = MFMA16(a1, bw1, acc);
    acc = MFMA16(a2, bw2, acc);
    float xm0 = fmaxf(acc[0], acc[1]);
    float xm1 = fmaxf(acc[2], acc[3]);
    float ym0 = fmaxf(xm0, __shfl_xor(xm0, 32));
    float ym1 = fmaxf(xm1, __shfl_xor(xm1, 32));
    if (l < 32) {
      int po = (p * 12 + xo * 4 + 2 * q) * 16 + lm;
      hout[po]      = f2b(fmaxf(ym0 + bias, 0.f));
      hout[po + 16] = f2b(fmaxf(ym1 + bias, 0.f));
    }
  }
}

// ============ conv2 implicit-GEMM MFMA -> feat FRAG ============
__global__ __launch_bounds__(256) void conv2_kernel(
    const u16* __restrict__ h1, const u16* __restrict__ W2colF,
    const float* __restrict__ b2, u16* __restrict__ feat) {
  __shared__ u16 ct[4][16][32];       // per-wave C repack tile
  int t = threadIdx.x;
  int w = t >> 6, l = t & 63;
  bf16x8 bfr[5][2];
#pragma unroll
  for (int s = 0; s < 5; s++)
#pragma unroll
    for (int nt = 0; nt < 2; nt++)
      bfr[s][nt] = *(const bf16x8*)(W2colF + ((size_t)(s * 2 + nt) * 64 + l) * 8);
  int lm = l & 15, lq = l >> 4, hi = l >> 5;
  int cib = (lq & 1) * 8;
  float bias0 = b2[lm], bias1 = b2[lm + 16];
  int g0 = blockIdx.x * 128 + w * 32;
#pragma unroll
  for (int sub = 0; sub < 2; sub++) {
    int g = g0 + sub * 16 + lm;
    uint32_t bimg = (uint32_t)(((uint64_t)(uint32_t)g * 1374389535ull) >> 37);  // g/100
    int p = g - (int)bimg * 100;
    int y = (p * 205) >> 11;          // p/10
    int xc = p - y * 10;
    const u16* base = h1 + (size_t)bimg * 2304;
    f32x4 acc0 = {0.f, 0.f, 0.f, 0.f}, acc1 = {0.f, 0.f, 0.f, 0.f};
#pragma unroll
    for (int s = 0; s < 5; s++) {
      int kk = 2 * s + hi;
      if (kk > 8) kk = 8;            // pad lanes: B-frag rows there are zero
      int ky = (kk * 11) >> 5;       // kk/3 for kk<=8
      int kx = kk - ky * 3;
      int off = ((y + ky) * 12 + (xc + kx)) * 16 + cib;
      bf16x8 a = *(const bf16x8*)(base + off);
      acc0 = MFMA16(a, bfr[s][0], acc0);
      acc1 = MFMA16(a, bfr[s][1], acc1);
    }
#pragma unroll
    for (int rr = 0; rr < 4; rr++) {
      ct[w][lq * 4 + rr][lm]      = f2b(fmaxf(acc0[rr] + bias0, 0.f));
      ct[w][lq * 4 + rr][lm + 16] = f2b(fmaxf(acc1[rr] + bias1, 0.f));
    }
    int gg = g0 + sub * 16 + (l >> 2);
    uint32_t bi2 = (uint32_t)(((uint64_t)(uint32_t)gg * 1374389535ull) >> 37);
    int pp = gg - (int)bi2 * 100;
    int mt2 = (int)(bi2 >> 6), rb = (int)((bi2 >> 4) & 3), lmr = (int)(bi2 & 15);
    uint4 v = *(const uint4*)&ct[w][l >> 2][(l & 3) * 8];
    *(uint4*)(feat + (((size_t)(mt2 * 100 + pp) * 4 + rb) << 9) +
              ((l & 3) * 16 + lmr) * 8) = v;
  }
}

// ============ gemm1: all-global streaming K-loop (no LDS, no barriers) ============
// grid 640: blk = mt + 128*e.  e1b = tanh(feat@W1e + b1) bf16 [8192][640].
// Fragments load straight from FRAG-layout global: coalesced dwordx4/lane,
// A dup x2 absorbed by L1, B (W1T, 4.1 MB) L2-resident.
__global__ __launch_bounds__(256, 4) void gemm1_kernel(
    const u16* __restrict__ feat, const u16* __restrict__ W1T,
    const u16* __restrict__ WcatT, const float* __restrict__ b1e,
    const float* __restrict__ bg, const float* __restrict__ bglu,
    u16* __restrict__ e1b, float* __restrict__ rw) {
  __shared__ u16 E1t[8192];             // epilogue transpose only (16 KB)
  __shared__ float RACC[1024];          // router partials (4 KB)
  int t = threadIdx.x, w = t >> 6, l = t & 63;
  int mt = blockIdx.x & 127;
  int e = blockIdx.x >> 7;
  size_t m0 = (size_t)mt * 64;
  int lm = l & 15, lq = l >> 4;
  int m_off = (w & 1) * 32, n_off = (w >> 1) * 64;
  bool rwave = (e == 0) && (w < 2);

  const u16* pA = feat + (size_t)mt * 204800 + ((w & 1) * 2) * 512 + l * 8;
  const u16* pB = W1T + (size_t)e * 409600 + ((w >> 1) * 4) * 512 + l * 8;
  const u16* pW = WcatT + l * 8;

  f32x4 acc[2][4] = {};
  f32x4 racc[2] = {};

#pragma unroll 2
  for (int s = 0; s < 100; s++) {
    bf16x8 af0 = *(const bf16x8*)(pA);
    bf16x8 af1 = *(const bf16x8*)(pA + 512);
    bf16x8 bf0 = *(const bf16x8*)(pB);
    bf16x8 bf1 = *(const bf16x8*)(pB + 512);
    bf16x8 bf2 = *(const bf16x8*)(pB + 1024);
    bf16x8 bf3 = *(const bf16x8*)(pB + 1536);
    acc[0][0] = MFMA16(af0, bf0, acc[0][0]);
    acc[0][1] = MFMA16(af0, bf1, acc[0][1]);
    acc[0][2] = MFMA16(af0, bf2, acc[0][2]);
    acc[0][3] = MFMA16(af0, bf3, acc[0][3]);
    acc[1][0] = MFMA16(af1, bf0, acc[1][0]);
    acc[1][1] = MFMA16(af1, bf1, acc[1][1]);
    acc[1][2] = MFMA16(af1, bf2, acc[1][2]);
    acc[1][3] = MFMA16(af1, bf3, acc[1][3]);
    if (rwave) {
      bf16x8 wf = *(const bf16x8*)(pW);
      racc[0] = MFMA16(af0, wf, racc[0]);
      racc[1] = MFMA16(af1, wf, racc[1]);
    }
    pA += 2048; pB += 4096; pW += 512;
  }

  // epilogue: tanh+bias -> bf16, LDS transpose for vectorized stores
  float b1v[4];
#pragma unroll
  for (int j = 0; j < 4; j++) b1v[j] = b1e[e * 128 + n_off + 16 * j + lm];
#pragma unroll
  for (int i = 0; i < 2; i++)
#pragma unroll
    for (int j = 0; j < 4; j++)
#pragma unroll
      for (int rr = 0; rr < 4; rr++) {
        int row = m_off + 16 * i + lq * 4 + rr;
        int col = n_off + 16 * j + lm;
        E1t[row * 128 + col] = f2b(tanhfast(acc[i][j][rr] + b1v[j]));
      }
  if (rwave) {
#pragma unroll
    for (int i = 0; i < 2; i++)
#pragma unroll
      for (int rr = 0; rr < 4; rr++)
        RACC[(m_off + 16 * i + lq * 4 + rr) * 16 + lm] = racc[i][rr];
  }
  __syncthreads();
#pragma unroll
  for (int k2 = 0; k2 < 4; k2++) {
    int u = t + k2 * 256;                      // 1024 segs of 16B
    int row = u >> 4, sc = u & 15;
    uint4 v = *(const uint4*)(E1t + row * 128 + sc * 8);
    *(uint4*)(e1b + (m0 + row) * 640 + e * 128 + sc * 8) = v;
  }
  if (e == 0 && t < 64) {
    float gt[5];
#pragma unroll
    for (int ee = 0; ee < 5; ee++) {
      float va = RACC[t * 16 + ee] + bg[ee];
      float vb = RACC[t * 16 + 5 + ee] + bglu[ee];
      gt[ee] = va * (1.f / (1.f + __expf(-vb)));
    }
    float w3[3]; int i3[3];
    unsigned used = 0;
#pragma unroll
    for (int k = 0; k < 3; k++) {
      float best = -1e30f; int bi = 0;
#pragma unroll
      for (int ee = 0; ee < 5; ee++)
        if (!((used >> ee) & 1u) && gt[ee] > best) { best = gt[ee]; bi = ee; }
      used |= 1u << bi; w3[k] = best; i3[k] = bi;
    }
    float s1 = __expf(w3[1] - w3[0]), s2 = __expf(w3[2] - w3[0]);
    float inv = 1.f / (1.f + s1 + s2);
    float o[5] = {0.f, 0.f, 0.f, 0.f, 0.f};
    o[i3[0]] = inv; o[i3[1]] = s1 * inv; o[i3[2]] = s2 * inv;
#pragma unroll
    for (int ee = 0; ee < 5; ee++) rw[(m0 + t) * 5 + ee] = o[ee];
  }
}

// ============ gemm2+combine+head: e1b@W2 -> tanh -> weighted sum -> Ws -> softmax ============
__global__ __launch_bounds__(256) void gemm2_head_kernel(
    const u16* __restrict__ e1b, const u16* __restrict__ W2T,
    const float* __restrict__ b2e, const float* __restrict__ rw,
    const float* __restrict__ Ws, const float* __restrict__ bs,
    float* __restrict__ out) {
  __shared__ u16 E1s[32][648];        // later overlaid by moes/parts
  __shared__ float wssh[1280];
  __shared__ float rws[160];
  int t = threadIdx.x;
  int r0 = blockIdx.x * 32;
  {
    int row = t >> 3;
    const u16* src = e1b + (size_t)(r0 + row) * 640 + (t & 7) * 8;
    u16* drow = &E1s[row][(t & 7) * 8];
#pragma unroll
    for (int k = 0; k < 10; k++)
      *(uint4*)(drow + k * 64) = *(const uint4*)(src + k * 64);
  }
  if (t < 160) rws[t] = rw[r0 * 5 + t];
  for (int i = t; i < 1280; i += 256) wssh[i] = Ws[i];
  __syncthreads();

  int w = t >> 6, l = t & 63, lm = l & 15, lq = l >> 4;
  int mh = w & 1, nh = w >> 1;
  f32x4 moeacc[4] = {};
#pragma unroll
  for (int e = 0; e < 5; e++) {
    f32x4 acc[4] = {};
    const u16* w2e = W2T + e * 16384;
#pragma unroll
    for (int kk = 0; kk < 4; kk++) {
      bf16x8 a = *(const bf16x8*)&E1s[mh * 16 + lm][e * 128 + kk * 32 + lq * 8];
#pragma unroll
      for (int j = 0; j < 4; j++) {
        bf16x8 b = *(const bf16x8*)(w2e + (nh * 64 + 16 * j + lm) * 128 + kk * 32 + lq * 8);
        acc[j] = MFMA16(a, b, acc[j]);
      }
    }
#pragma unroll
    for (int j = 0; j < 4; j++) {
      float b2v = b2e[e * 128 + nh * 64 + 16 * j + lm];
#pragma unroll
      for (int rr = 0; rr < 4; rr++) {
        float v = tanhfast(acc[j][rr] + b2v);
        moeacc[j][rr] += rws[(mh * 16 + lq * 4 + rr) * 5 + e] * v;
      }
    }
  }
  __syncthreads();                     // done reading E1s
  float* moes = (float*)&E1s[0][0];    // [32][132]
#pragma unroll
  for (int j = 0; j < 4; j++)
#pragma unroll
    for (int rr = 0; rr < 4; rr++)
      moes[(mh * 16 + lq * 4 + rr) * 132 + nh * 64 + 16 * j + lm] = moeacc[j][rr];
  __syncthreads();
  float* parts = moes + 32 * 132;      // [32][4][10]
  if (t < 128) {
    int row = t >> 2, qc = t & 3;
    float pl[10] = {};
    for (int cc = qc * 32; cc < qc * 32 + 32; cc++) {
      float mv = moes[row * 132 + cc];
#pragma unroll
      for (int cls = 0; cls < 10; cls++) pl[cls] += mv * wssh[cc * 10 + cls];
    }
#pragma unroll
    for (int cls = 0; cls < 10; cls++) parts[(row * 4 + qc) * 10 + cls] = pl[cls];
  }
  __syncthreads();
  if (t < 32) {
    float lg[10];
    float mx = -1e30f;
#pragma unroll
    for (int cls = 0; cls < 10; cls++) {
      lg[cls] = parts[(t * 4) * 10 + cls] + parts[(t * 4 + 1) * 10 + cls] +
                parts[(t * 4 + 2) * 10 + cls] + parts[(t * 4 + 3) * 10 + cls] + bs[cls];
      mx = fmaxf(mx, lg[cls]);
    }
    float sum = 0.f;
#pragma unroll
    for (int cls = 0; cls < 10; cls++) { lg[cls] = __expf(lg[cls] - mx); sum += lg[cls]; }
    float inv = 1.f / sum;
    float* orow = out + (size_t)(r0 + t) * 10;
#pragma unroll
    for (int cls = 0; cls < 10; cls++) orow[cls] = lg[cls] * inv;
  }
}

extern "C" void kernel_launch(void* const* d_in, const int* in_sizes, int n_in,
                              void* d_out, int out_size, void* d_ws, size_t ws_size,
                              hipStream_t stream) {
  const float* x    = (const float*)d_in[0];
  const float* c1w  = (const float*)d_in[1];
  const float* c1b  = (const float*)d_in[2];
  const float* c2w  = (const float*)d_in[3];
  const float* c2b  = (const float*)d_in[4];
  const float* Wg   = (const float*)d_in[5];
  const float* bg   = (const float*)d_in[6];
  const float* Wglu = (const float*)d_in[7];
  const float* bglu = (const float*)d_in[8];
  const float* W1e  = (const float*)d_in[9];
  const float* b1e  = (const float*)d_in[10];
  const float* W2e  = (const float*)d_in[11];
  const float* b2e  = (const float*)d_in[12];
  const float* Wsp  = (const float*)d_in[13];
  const float* bsp  = (const float*)d_in[14];
  char* ws = (char*)d_ws;
  u16* h1      = (u16*)(ws + 0);
  u16* e1b     = (u16*)(ws + 0);            // overlays h1 (dead after conv2)
  u16* feat    = (u16*)(ws + 37748736);
  u16* W1T     = (u16*)(ws + 90177536);
  u16* W2T     = (u16*)(ws + 94273536);
  u16* W2colF  = (u16*)(ws + 94437376);
  u16* WcatT   = (u16*)(ws + 94447616);
  float* rw    = (float*)(ws + 94550016);

  prep_misc_kernel<<<540, 256, 0, stream>>>(c2w, Wg, Wglu, W2e, W2colF, WcatT, W2T);
  prep_w1t_kernel<<<250, 256, 0, stream>>>(W1e, W1T);
  conv1_kernel<<<8192, 256, 0, stream>>>(x, c1w, c1b, h1);
  conv2_kernel<<<6400, 256, 0, stream>>>(h1, W2colF, c2b, feat);
  gemm1_kernel<<<640, 256, 0, stream>>>(feat, W1T, WcatT, b1e, bg, bglu, e1b, rw);
  gemm2_head_kernel<<<256, 256, 0, stream>>>(e1b, W2T, b2e, rw, Wsp, bsp,
                                             (float*)d_out);
}

// Round 10
// 211.339 us; speedup vs baseline: 1.2791x; 1.2791x over previous
//
#include <hip/hip_runtime.h>
#include <stdint.h>

typedef unsigned short u16;
typedef __attribute__((ext_vector_type(8))) short bf16x8;   // 8 bf16 = 4 VGPRs
typedef __attribute__((ext_vector_type(4))) float f32x4;

#define MFMA16(a, b, c) __builtin_amdgcn_mfma_f32_16x16x32_bf16((a), (b), (c), 0, 0, 0)
#define GLD16(gp, lp) __builtin_amdgcn_global_load_lds( \
    (__attribute__((address_space(1))) void*)(gp), \
    (__attribute__((address_space(3))) void*)(lp), 16, 0, 0)

__device__ __forceinline__ u16 f2b(float f) {   // fp32 -> bf16 RNE
  uint32_t u = __float_as_uint(f);
  u += 0x7FFFu + ((u >> 16) & 1u);
  return (u16)(u >> 16);
}
__device__ __forceinline__ float tanhfast(float x) {
  float e = __expf(2.f * x);
  return (e - 1.f) / (e + 1.f);
}

// ---------------- workspace layout (bytes) ----------------
// e1b bf16 [8192][640]              @ 0          10,485,760
// feat FRAG [128 mt][100 s][4 rb][64 l][8]  @ 37748736  52,428,800
// W1T FRAG [5 e][100 s][8 nb][64 l][8]      @ 90177536   4,096,000
// W2T bf16 [5][128][128]            @ 94273536      163,840
// W2colF bf16 [5][2][64][8]         @ 94437376       10,240
// WcatT FRAG [100 s][64 l][8]       @ 94447616      102,400
// rw f32 [8192][5]                  @ 94550016      163,840   (total 94.7 MB)

// ============ prep_misc: small weight repacks ============
__global__ __launch_bounds__(256) void prep_misc_kernel(
    const float* __restrict__ c2w, const float* __restrict__ Wg,
    const float* __restrict__ Wglu, const float* __restrict__ W2e,
    u16* __restrict__ W2colF, u16* __restrict__ WcatT, u16* __restrict__ W2T) {
  int i = blockIdx.x * 256 + threadIdx.x;
  if (i < 5120) {                       // conv2 B-fragments, k=(ky*3+kx)*16+ci, pad->160
    int j = i & 7, l = (i >> 3) & 63, nt = (i >> 9) & 1, s = i >> 10;
    int k = s * 32 + ((l >> 4) & 3) * 8 + j;
    int n = (l & 15) + nt * 16;
    float v = 0.f;
    if (k < 144) {
      int kykx = k >> 4, ci = k & 15;
      int ky = kykx / 3, kx = kykx - ky * 3;
      v = c2w[((n * 16 + ci) * 3 + ky) * 3 + kx];
    }
    W2colF[i] = f2b(v);
  } else if (i < 56320) {               // WcatT FRAG [s][l][8]
    int o = i - 5120;
    int s = o >> 9, rest = o & 511;
    int l = rest >> 3, j = rest & 7;
    int r = l & 15, c = (l >> 4) * 8 + j;
    int dref = c * 100 + s;
    float v = 0.f;
    if (r < 5) v = Wg[dref * 5 + r];
    else if (r < 10) v = Wglu[dref * 5 + (r - 5)];
    WcatT[o] = f2b(v);
  } else if (i < 138240) {              // W2T[e][g][h]
    int o = i - 56320;
    int e = o >> 14, rem = o & 16383;
    int g = rem >> 7, h = rem & 127;
    W2T[o] = f2b(W2e[(e * 128 + h) * 128 + g]);
  }
}

// ============ prep_w1t: W1e[e][d][n] -> W1T FRAG [e][s][nb][l][8] ============
__global__ __launch_bounds__(256) void prep_w1t_kernel(
    const float* __restrict__ W1e, u16* __restrict__ W1T) {
  __shared__ u16 ts[64][128];           // [ph*32+c][n]
  int t = threadIdx.x;
  int e = blockIdx.x / 50, pt = blockIdx.x % 50;   // 2 p-values per block
  {
    int r64 = t >> 2;                   // 0..63: ph = r64>>5, c = r64&31
    int ph = r64 >> 5, c = r64 & 31;
    int d = c * 100 + pt * 2 + ph;
    const float* src = W1e + ((size_t)e * 3200 + d) * 128 + (t & 3) * 32;
    u16* drow = &ts[r64][(t & 3) * 32];
#pragma unroll
    for (int u = 0; u < 8; u++) {
      float4 v = *(const float4*)(src + u * 4);
      drow[u * 4 + 0] = f2b(v.x); drow[u * 4 + 1] = f2b(v.y);
      drow[u * 4 + 2] = f2b(v.z); drow[u * 4 + 3] = f2b(v.w);
    }
  }
  __syncthreads();
#pragma unroll
  for (int k = 0; k < 4; k++) {
    int u = t + k * 256;                // 1024 chunks of 16 B
    int ph = u >> 9, nb = (u >> 6) & 7, l = u & 63;
    int lm = l & 15, lqf = l >> 4;
    u16 tmp[8];
#pragma unroll
    for (int j = 0; j < 8; j++)
      tmp[j] = ts[ph * 32 + lqf * 8 + j][nb * 16 + lm];
    *(uint4*)(W1T + (((size_t)((e * 100 + pt * 2 + ph) * 8 + nb)) << 9) + l * 8) =
        *(const uint4*)tmp;
  }
}

// ============ fused conv1(MFMA+pool, ->LDS) + conv2(MFMA, ->feat FRAG) ============
// One block = one image. cp = 8 shifted bf16 image copies; h1s = pooled 12x12x16;
// ct (C-repack) overlays cp (dead after phase 1).
__global__ __launch_bounds__(256) void conv_fused_kernel(
    const float* __restrict__ x, const float* __restrict__ w1,
    const float* __restrict__ b1, const u16* __restrict__ W2colF,
    const float* __restrict__ b2, u16* __restrict__ feat) {
  __shared__ __align__(16) u16 cp[7232];   // [8 copies][28 rows][32], stride 904
  __shared__ __align__(16) u16 h1s[2304];  // pooled [12][12][16]
  int t = threadIdx.x, b = blockIdx.x, w = t >> 6, l = t & 63;

  if (t < 84) {                            // stage shifted copies from registers
    int r = (t * 171) >> 9;                // t/3
    int o = t - r * 3;                     // octet 0..2
    const float4* src = (const float4*)(x + (size_t)b * 784 + r * 28 + o * 8);
    float4 qa = src[0], qb = src[1], qc = src[2];
    float4 qd = {0.f, 0.f, 0.f, 0.f};
    if (o < 2) qd = src[3];
    uint32_t d0 = (uint32_t)f2b(qa.x) | ((uint32_t)f2b(qa.y) << 16);
    uint32_t d1 = (uint32_t)f2b(qa.z) | ((uint32_t)f2b(qa.w) << 16);
    uint32_t d2 = (uint32_t)f2b(qb.x) | ((uint32_t)f2b(qb.y) << 16);
    uint32_t d3 = (uint32_t)f2b(qb.z) | ((uint32_t)f2b(qb.w) << 16);
    uint32_t d4 = (uint32_t)f2b(qc.x) | ((uint32_t)f2b(qc.y) << 16);
    uint32_t d5 = (uint32_t)f2b(qc.z) | ((uint32_t)f2b(qc.w) << 16);
    uint32_t d6 = (uint32_t)f2b(qd.x) | ((uint32_t)f2b(qd.y) << 16);
    uint32_t d7 = (uint32_t)f2b(qd.z) | ((uint32_t)f2b(qd.w) << 16);
#define SH(hi, lo) (((lo) >> 16) | ((hi) << 16))
    int base = r * 32 + o * 8;
    *(uint4*)&cp[base + 0 * 904] = uint4{d0, d1, d2, d3};
    *(uint4*)&cp[base + 1 * 904] = uint4{SH(d1, d0), SH(d2, d1), SH(d3, d2), SH(d4, d3)};
    *(uint4*)&cp[base + 2 * 904] = uint4{d1, d2, d3, d4};
    *(uint4*)&cp[base + 3 * 904] = uint4{SH(d2, d1), SH(d3, d2), SH(d4, d3), SH(d5, d4)};
    *(uint4*)&cp[base + 4 * 904] = uint4{d2, d3, d4, d5};
    *(uint4*)&cp[base + 5 * 904] = uint4{SH(d3, d2), SH(d4, d3), SH(d5, d4), SH(d6, d5)};
    *(uint4*)&cp[base + 6 * 904] = uint4{d3, d4, d5, d6};
    *(uint4*)&cp[base + 7 * 904] = uint4{SH(d4, d3), SH(d5, d4), SH(d6, d5), SH(d7, d6)};
#undef SH
  }

  int lm = l & 15, c = l & 7, ry = (l >> 3) & 1, q = l >> 4;
  bf16x8 bw1 = {0, 0, 0, 0, 0, 0, 0, 0}, bw2 = {0, 0, 0, 0, 0, 0, 0, 0};
#pragma unroll
  for (int j = 0; j < 5; j++) {
    bw1[j] = (short)f2b(w1[lm * 25 + q * 5 + j]);
    if (q == 0) bw2[j] = (short)f2b(w1[lm * 25 + 20 + j]);
  }
  float bias = b1[lm];
  __syncthreads();

#pragma unroll
  for (int i = 0; i < 9; i++) {
    int tt = i * 4 + w;                   // 36 tiles: p (pool-row) x xo (x-octet)
    int p = (tt * 171) >> 9;              // tt/3
    int xo = tt - p * 3;
    int r1 = p * 2 + ry + q;              // <= 26
    int r2 = min(r1 + 4, 27);             // clamp: rows >27 have zero weights
    bf16x8 a1 = *(const bf16x8*)&cp[c * 904 + r1 * 32 + xo * 8];
    bf16x8 a2 = *(const bf16x8*)&cp[c * 904 + r2 * 32 + xo * 8];
    f32x4 acc = {0.f, 0.f, 0.f, 0.f};
    acc = MFMA16(a1, bw1, acc);
    acc = MFMA16(a2, bw2, acc);
    float xm0 = fmaxf(acc[0], acc[1]);
    float xm1 = fmaxf(acc[2], acc[3]);
    float ym0 = fmaxf(xm0, __shfl_xor(xm0, 32));
    float ym1 = fmaxf(xm1, __shfl_xor(xm1, 32));
    if (l < 32) {
      int po = (p * 12 + xo * 4 + 2 * q) * 16 + lm;
      h1s[po]      = f2b(fmaxf(ym0 + bias, 0.f));
      h1s[po + 16] = f2b(fmaxf(ym1 + bias, 0.f));
    }
  }

  // ---- phase 2: conv2 on the LDS image ----
  bf16x8 bfr[5][2];
#pragma unroll
  for (int s = 0; s < 5; s++)
#pragma unroll
    for (int nt = 0; nt < 2; nt++)
      bfr[s][nt] = *(const bf16x8*)(W2colF + ((size_t)(s * 2 + nt) * 64 + l) * 8);
  int lq = l >> 4, hi = l >> 5;
  int cib = (lq & 1) * 8;
  float bias0 = b2[lm], bias1 = b2[lm + 16];
  int mt2 = b >> 6, rb = (b >> 4) & 3, lmr = b & 15;
  u16* ct = cp;                           // per-wave [16][32] repack tiles (cp dead)
  __syncthreads();

  for (int ti = w; ti < 7; ti += 4) {     // 7 tiles of 16 positions (112 padded)
    int p = ti * 16 + lm;
    int pc = p < 100 ? p : 99;            // clamp pad lanes (results discarded)
    int y = (pc * 205) >> 11;             // pc/10
    int xc = pc - y * 10;
    f32x4 acc0 = {0.f, 0.f, 0.f, 0.f}, acc1 = {0.f, 0.f, 0.f, 0.f};
#pragma unroll
    for (int s = 0; s < 5; s++) {
      int kk = 2 * s + hi;
      if (kk > 8) kk = 8;                 // pad lanes: B-frag rows there are zero
      int ky = (kk * 11) >> 5;            // kk/3 for kk<=8
      int kx = kk - ky * 3;
      int off = ((y + ky) * 12 + (xc + kx)) * 16 + cib;
      bf16x8 a = *(const bf16x8*)&h1s[off];
      acc0 = MFMA16(a, bfr[s][0], acc0);
      acc1 = MFMA16(a, bfr[s][1], acc1);
    }
#pragma unroll
    for (int rr = 0; rr < 4; rr++) {
      ct[w * 512 + (lq * 4 + rr) * 32 + lm]      = f2b(fmaxf(acc0[rr] + bias0, 0.f));
      ct[w * 512 + (lq * 4 + rr) * 32 + lm + 16] = f2b(fmaxf(acc1[rr] + bias1, 0.f));
    }
    int pp = ti * 16 + (l >> 2);
    if (pp < 100) {
      uint4 v = *(const uint4*)&ct[w * 512 + (l >> 2) * 32 + (l & 3) * 8];
      *(uint4*)(feat + (((size_t)(mt2 * 100 + pp) * 4 + rb) << 9) +
                ((l & 3) * 16 + lmr) * 8) = v;
    }
  }
}

// ============ gemm1: 64x128 tile, BK=32 GLD16 double-buffer, fused tanh + router ============
// grid 640: blk = mt + 128*e.  e1b = tanh(feat@W1e + b1) bf16 [8192][640].
#define GEMM1_KLOOP(HASW, VMCSTR)                                              \
  {                                                                            \
    GLD16(pA, &lds[0][w * 512]);                                               \
    GLD16(pB1, &lds[0][2048 + w * 512]);                                       \
    GLD16(pB2, &lds[0][4096 + w * 512]);                                       \
    if (HASW) GLD16(pW, &lds[0][6144]);                                        \
    pA += 2048; pB1 += 4096; pB2 += 4096; pW += 512;                           \
    for (int s = 0; s < 100; s++) {                                            \
      int buf = s & 1;                                                         \
      if (s < 99) {                                                            \
        GLD16(pA, &lds[buf ^ 1][w * 512]);                                     \
        GLD16(pB1, &lds[buf ^ 1][2048 + w * 512]);                             \
        GLD16(pB2, &lds[buf ^ 1][4096 + w * 512]);                             \
        if (HASW) GLD16(pW, &lds[buf ^ 1][6144]);                              \
        pA += 2048; pB1 += 4096; pB2 += 4096; pW += 512;                       \
        asm volatile("s_waitcnt " VMCSTR ::: "memory");                        \
      } else {                                                                 \
        asm volatile("s_waitcnt vmcnt(0)" ::: "memory");                       \
      }                                                                        \
      asm volatile("s_barrier" ::: "memory");                                  \
      const u16* st = &lds[buf][0];                                            \
      bf16x8 af[2], bf[4];                                                     \
      _Pragma("unroll")                                                        \
      for (int i = 0; i < 2; i++)                                              \
        af[i] = *(const bf16x8*)(st + ((w & 1) * 2 + i) * 512 + l * 8);        \
      _Pragma("unroll")                                                        \
      for (int j = 0; j < 4; j++)                                              \
        bf[j] = *(const bf16x8*)(st + 2048 + ((w >> 1) * 4 + j) * 512 + l * 8);\
      _Pragma("unroll")                                                        \
      for (int i = 0; i < 2; i++)                                              \
        _Pragma("unroll")                                                      \
        for (int j = 0; j < 4; j++)                                            \
          acc[i][j] = MFMA16(af[i], bf[j], acc[i][j]);                         \
      if (HASW && w < 2) {                                                     \
        bf16x8 wf = *(const bf16x8*)(st + 6144 + l * 8);                       \
        racc[0] = MFMA16(af[0], wf, racc[0]);                                  \
        racc[1] = MFMA16(af[1], wf, racc[1]);                                  \
      }                                                                        \
      asm volatile("s_barrier" ::: "memory");                                  \
    }                                                                          \
  }

__global__ __launch_bounds__(256, 3) void gemm1_kernel(
    const u16* __restrict__ feat, const u16* __restrict__ W1T,
    const u16* __restrict__ WcatT, const float* __restrict__ b1e,
    const float* __restrict__ bg, const float* __restrict__ bglu,
    u16* __restrict__ e1b, float* __restrict__ rw) {
  __shared__ u16 lds[2][6656];          // per buf: A 4x512 | B 8x512 | W 512
  int t = threadIdx.x, w = t >> 6, l = t & 63;
  int mt = blockIdx.x & 127;
  int e = blockIdx.x >> 7;
  size_t m0 = (size_t)mt * 64;
  int lm = l & 15, lq = l >> 4;
  int m_off = (w & 1) * 32, n_off = (w >> 1) * 64;

  const u16* pA = feat + (size_t)mt * 204800 + w * 512 + l * 8;
  const u16* pB1 = W1T + (size_t)e * 409600 + w * 512 + l * 8;
  const u16* pB2 = pB1 + 2048;          // nb = 4+w
  const u16* pW = WcatT + l * 8;

  f32x4 acc[2][4] = {};
  f32x4 racc[2] = {};

  if (e == 0) GEMM1_KLOOP(true, "vmcnt(4)")
  else        GEMM1_KLOOP(false, "vmcnt(3)")

  // epilogue: tanh+bias -> bf16, LDS transpose for vectorized stores
  float b1v[4];
#pragma unroll
  for (int j = 0; j < 4; j++) b1v[j] = b1e[e * 128 + n_off + 16 * j + lm];
  u16* E1t = &lds[0][0];             // [64][128] u16 = 16 KB
#pragma unroll
  for (int i = 0; i < 2; i++)
#pragma unroll
    for (int j = 0; j < 4; j++)
#pragma unroll
      for (int rr = 0; rr < 4; rr++) {
        int row = m_off + 16 * i + lq * 4 + rr;
        int col = n_off + 16 * j + lm;
        E1t[row * 128 + col] = f2b(tanhfast(acc[i][j][rr] + b1v[j]));
      }
  if (e == 0 && w < 2) {
    float* RACC = (float*)((char*)lds + 20480);    // [64][16] f32
#pragma unroll
    for (int i = 0; i < 2; i++)
#pragma unroll
      for (int rr = 0; rr < 4; rr++)
        RACC[(m_off + 16 * i + lq * 4 + rr) * 16 + lm] = racc[i][rr];
  }
  __syncthreads();
#pragma unroll
  for (int k2 = 0; k2 < 4; k2++) {
    int u = t + k2 * 256;                      // 1024 segs of 16B
    int row = u >> 4, sc = u & 15;
    uint4 v = *(const uint4*)(E1t + row * 128 + sc * 8);
    *(uint4*)(e1b + (m0 + row) * 640 + e * 128 + sc * 8) = v;
  }
  if (e == 0 && t < 64) {
    const float* RACC = (const float*)((char*)lds + 20480);
    float gt[5];
#pragma unroll
    for (int ee = 0; ee < 5; ee++) {
      float va = RACC[t * 16 + ee] + bg[ee];
      float vb = RACC[t * 16 + 5 + ee] + bglu[ee];
      gt[ee] = va * (1.f / (1.f + __expf(-vb)));
    }
    float w3[3]; int i3[3];
    unsigned used = 0;
#pragma unroll
    for (int k = 0; k < 3; k++) {
      float best = -1e30f; int bi = 0;
#pragma unroll
      for (int ee = 0; ee < 5; ee++)
        if (!((used >> ee) & 1u) && gt[ee] > best) { best = gt[ee]; bi = ee; }
      used |= 1u << bi; w3[k] = best; i3[k] = bi;
    }
    float s1 = __expf(w3[1] - w3[0]), s2 = __expf(w3[2] - w3[0]);
    float inv = 1.f / (1.f + s1 + s2);
    float o[5] = {0.f, 0.f, 0.f, 0.f, 0.f};
    o[i3[0]] = inv; o[i3[1]] = s1 * inv; o[i3[2]] = s2 * inv;
#pragma unroll
    for (int ee = 0; ee < 5; ee++) rw[(m0 + t) * 5 + ee] = o[ee];
  }
}

// ============ gemm2+combine+head: e1b@W2 -> tanh -> weighted sum -> Ws -> softmax ============
__global__ __launch_bounds__(256) void gemm2_head_kernel(
    const u16* __restrict__ e1b, const u16* __restrict__ W2T,
    const float* __restrict__ b2e, const float* __restrict__ rw,
    const float* __restrict__ Ws, const float* __restrict__ bs,
    float* __restrict__ out) {
  __shared__ u16 E1s[32][648];        // later overlaid by moes/parts
  __shared__ float wssh[1280];
  __shared__ float rws[160];
  int t = threadIdx.x;
  int r0 = blockIdx.x * 32;
  {
    int row = t >> 3;
    const u16* src = e1b + (size_t)(r0 + row) * 640 + (t & 7) * 8;
    u16* drow = &E1s[row][(t & 7) * 8];
#pragma unroll
    for (int k = 0; k < 10; k++)
      *(uint4*)(drow + k * 64) = *(const uint4*)(src + k * 64);
  }
  if (t < 160) rws[t] = rw[r0 * 5 + t];
  for (int i = t; i < 1280; i += 256) wssh[i] = Ws[i];
  __syncthreads();

  int w = t >> 6, l = t & 63, lm = l & 15, lq = l >> 4;
  int mh = w & 1, nh = w >> 1;
  f32x4 moeacc[4] = {};
#pragma unroll
  for (int e = 0; e < 5; e++) {
    f32x4 acc[4] = {};
    const u16* w2e = W2T + e * 16384;
#pragma unroll
    for (int kk = 0; kk < 4; kk++) {
      bf16x8 a = *(const bf16x8*)&E1s[mh * 16 + lm][e * 128 + kk * 32 + lq * 8];
#pragma unroll
      for (int j = 0; j < 4; j++) {
        bf16x8 b = *(const bf16x8*)(w2e + (nh * 64 + 16 * j + lm) * 128 + kk * 32 + lq * 8);
        acc[j] = MFMA16(a, b, acc[j]);
      }
    }
#pragma unroll
    for (int j = 0; j < 4; j++) {
      float b2v = b2e[e * 128 + nh * 64 + 16 * j + lm];
#pragma unroll
      for (int rr = 0; rr < 4; rr++) {
        float v = tanhfast(acc[j][rr] + b2v);
        moeacc[j][rr] += rws[(mh * 16 + lq * 4 + rr) * 5 + e] * v;
      }
    }
  }
  __syncthreads();                     // done reading E1s
  float* moes = (float*)&E1s[0][0];    // [32][132]
#pragma unroll
  for (int j = 0; j < 4; j++)
#pragma unroll
    for (int rr = 0; rr < 4; rr++)
      moes[(mh * 16 + lq * 4 + rr) * 132 + nh * 64 + 16 * j + lm] = moeacc[j][rr];
  __syncthreads();
  float* parts = moes + 32 * 132;      // [32][4][10]
  if (t < 128) {
    int row = t >> 2, qc = t & 3;
    float pl[10] = {};
    for (int cc = qc * 32; cc < qc * 32 + 32; cc++) {
      float mv = moes[row * 132 + cc];
#pragma unroll
      for (int cls = 0; cls < 10; cls++) pl[cls] += mv * wssh[cc * 10 + cls];
    }
#pragma unroll
    for (int cls = 0; cls < 10; cls++) parts[(row * 4 + qc) * 10 + cls] = pl[cls];
  }
  __syncthreads();
  if (t < 32) {
    float lg[10];
    float mx = -1e30f;
#pragma unroll
    for (int cls = 0; cls < 10; cls++) {
      lg[cls] = parts[(t * 4) * 10 + cls] + parts[(t * 4 + 1) * 10 + cls] +
                parts[(t * 4 + 2) * 10 + cls] + parts[(t * 4 + 3) * 10 + cls] + bs[cls];
      mx = fmaxf(mx, lg[cls]);
    }
    float sum = 0.f;
#pragma unroll
    for (int cls = 0; cls < 10; cls++) { lg[cls] = __expf(lg[cls] - mx); sum += lg[cls]; }
    float inv = 1.f / sum;
    float* orow = out + (size_t)(r0 + t) * 10;
#pragma unroll
    for (int cls = 0; cls < 10; cls++) orow[cls] = lg[cls] * inv;
  }
}

extern "C" void kernel_launch(void* const* d_in, const int* in_sizes, int n_in,
                              void* d_out, int out_size, void* d_ws, size_t ws_size,
                              hipStream_t stream) {
  const float* x    = (const float*)d_in[0];
  const float* c1w  = (const float*)d_in[1];
  const float* c1b  = (const float*)d_in[2];
  const float* c2w  = (const float*)d_in[3];
  const float* c2b  = (const float*)d_in[4];
  const float* Wg   = (const float*)d_in[5];
  const float* bg   = (const float*)d_in[6];
  const float* Wglu = (const float*)d_in[7];
  const float* bglu = (const float*)d_in[8];
  const float* W1e  = (const float*)d_in[9];
  const float* b1e  = (const float*)d_in[10];
  const float* W2e  = (const float*)d_in[11];
  const float* b2e  = (const float*)d_in[12];
  const float* Wsp  = (const float*)d_in[13];
  const float* bsp  = (const float*)d_in[14];
  char* ws = (char*)d_ws;
  u16* e1b     = (u16*)(ws + 0);
  u16* feat    = (u16*)(ws + 37748736);
  u16* W1T     = (u16*)(ws + 90177536);
  u16* W2T     = (u16*)(ws + 94273536);
  u16* W2colF  = (u16*)(ws + 94437376);
  u16* WcatT   = (u16*)(ws + 94447616);
  float* rw    = (float*)(ws + 94550016);

  prep_misc_kernel<<<540, 256, 0, stream>>>(c2w, Wg, Wglu, W2e, W2colF, WcatT, W2T);
  prep_w1t_kernel<<<250, 256, 0, stream>>>(W1e, W1T);
  conv_fused_kernel<<<8192, 256, 0, stream>>>(x, c1w, c1b, W2colF, c2b, feat);
  gemm1_kernel<<<640, 256, 0, stream>>>(feat, W1T, WcatT, b1e, bg, bglu, e1b, rw);
  gemm2_head_kernel<<<256, 256, 0, stream>>>(e1b, W2T, b2e, rw, Wsp, bsp,
                                             (float*)d_out);
}

// Round 11
// 207.325 us; speedup vs baseline: 1.3038x; 1.0194x over previous
//
#include <hip/hip_runtime.h>
#include <stdint.h>

typedef unsigned short u16;
typedef __attribute__((ext_vector_type(8))) short bf16x8;   // 8 bf16 = 4 VGPRs
typedef __attribute__((ext_vector_type(4))) float f32x4;

#define MFMA16(a, b, c) __builtin_amdgcn_mfma_f32_16x16x32_bf16((a), (b), (c), 0, 0, 0)
#define GLD16(gp, lp) __builtin_amdgcn_global_load_lds( \
    (__attribute__((address_space(1))) void*)(gp), \
    (__attribute__((address_space(3))) void*)(lp), 16, 0, 0)

__device__ __forceinline__ u16 f2b(float f) {   // fp32 -> bf16 RNE
  uint32_t u = __float_as_uint(f);
  u += 0x7FFFu + ((u >> 16) & 1u);
  return (u16)(u >> 16);
}
__device__ __forceinline__ float tanhfast(float x) {
  float e = __expf(2.f * x);
  return (e - 1.f) / (e + 1.f);
}

// ---------------- workspace layout (bytes) ----------------
// e1b bf16 [8192][640]              @ 0          10,485,760
// feat FRAG [128 mt][100 s][4 rb][64 l][8]  @ 37748736  52,428,800
// W1T FRAG [5 e][100 s][8 nb][64 l][8]      @ 90177536   4,096,000
// W2T bf16 [5][128][128]            @ 94273536      163,840
// W2colF bf16 [5][2][64][8]         @ 94437376       10,240
// WcatT FRAG [100 s][64 l][8]       @ 94447616      102,400
// rw f32 [8192][5]                  @ 94550016      163,840   (total 94.7 MB)

// ============ prep_misc: small weight repacks ============
__global__ __launch_bounds__(256) void prep_misc_kernel(
    const float* __restrict__ c2w, const float* __restrict__ Wg,
    const float* __restrict__ Wglu, const float* __restrict__ W2e,
    u16* __restrict__ W2colF, u16* __restrict__ WcatT, u16* __restrict__ W2T) {
  int i = blockIdx.x * 256 + threadIdx.x;
  if (i < 5120) {                       // conv2 B-fragments, k=(ky*3+kx)*16+ci, pad->160
    int j = i & 7, l = (i >> 3) & 63, nt = (i >> 9) & 1, s = i >> 10;
    int k = s * 32 + ((l >> 4) & 3) * 8 + j;
    int n = (l & 15) + nt * 16;
    float v = 0.f;
    if (k < 144) {
      int kykx = k >> 4, ci = k & 15;
      int ky = kykx / 3, kx = kykx - ky * 3;
      v = c2w[((n * 16 + ci) * 3 + ky) * 3 + kx];
    }
    W2colF[i] = f2b(v);
  } else if (i < 56320) {               // WcatT FRAG [s][l][8]
    int o = i - 5120;
    int s = o >> 9, rest = o & 511;
    int l = rest >> 3, j = rest & 7;
    int r = l & 15, c = (l >> 4) * 8 + j;
    int dref = c * 100 + s;
    float v = 0.f;
    if (r < 5) v = Wg[dref * 5 + r];
    else if (r < 10) v = Wglu[dref * 5 + (r - 5)];
    WcatT[o] = f2b(v);
  } else if (i < 138240) {              // W2T[e][g][h]
    int o = i - 56320;
    int e = o >> 14, rem = o & 16383;
    int g = rem >> 7, h = rem & 127;
    W2T[o] = f2b(W2e[(e * 128 + h) * 128 + g]);
  }
}

// ============ prep_w1t: W1e[e][d][n] -> W1T FRAG [e][s][nb][l][8] ============
__global__ __launch_bounds__(256) void prep_w1t_kernel(
    const float* __restrict__ W1e, u16* __restrict__ W1T) {
  __shared__ u16 ts[64][128];           // [ph*32+c][n]
  int t = threadIdx.x;
  int e = blockIdx.x / 50, pt = blockIdx.x % 50;   // 2 p-values per block
  {
    int r64 = t >> 2;                   // 0..63: ph = r64>>5, c = r64&31
    int ph = r64 >> 5, c = r64 & 31;
    int d = c * 100 + pt * 2 + ph;
    const float* src = W1e + ((size_t)e * 3200 + d) * 128 + (t & 3) * 32;
    u16* drow = &ts[r64][(t & 3) * 32];
#pragma unroll
    for (int u = 0; u < 8; u++) {
      float4 v = *(const float4*)(src + u * 4);
      drow[u * 4 + 0] = f2b(v.x); drow[u * 4 + 1] = f2b(v.y);
      drow[u * 4 + 2] = f2b(v.z); drow[u * 4 + 3] = f2b(v.w);
    }
  }
  __syncthreads();
#pragma unroll
  for (int k = 0; k < 4; k++) {
    int u = t + k * 256;                // 1024 chunks of 16 B
    int ph = u >> 9, nb = (u >> 6) & 7, l = u & 63;
    int lm = l & 15, lqf = l >> 4;
    u16 tmp[8];
#pragma unroll
    for (int j = 0; j < 8; j++)
      tmp[j] = ts[ph * 32 + lqf * 8 + j][nb * 16 + lm];
    *(uint4*)(W1T + (((size_t)((e * 100 + pt * 2 + ph) * 8 + nb)) << 9) + l * 8) =
        *(const uint4*)tmp;
  }
}

// ============ fused conv1(MFMA+pool, ->LDS) + conv2(MFMA, ->feat FRAG) ============
// One block = one image. cp = 8 shifted bf16 image copies; h1s = pooled 12x12,
// position stride 24 u16 (48 B => conflict-free b128); ct overlays cp.
__global__ __launch_bounds__(256) void conv_fused_kernel(
    const float* __restrict__ x, const float* __restrict__ w1,
    const float* __restrict__ b1, const u16* __restrict__ W2colF,
    const float* __restrict__ b2, u16* __restrict__ feat) {
  __shared__ __align__(16) u16 cp[7232];   // [8 copies][28 rows][32], stride 904
  __shared__ __align__(16) u16 h1s[3456];  // pooled [144 pos][24]
  int t = threadIdx.x, b = blockIdx.x, w = t >> 6, l = t & 63;
  int lm = l & 15;

  // conv2 B-frags issued first: L2 latency hides under phase 1
  bf16x8 bfr[5][2];
#pragma unroll
  for (int s = 0; s < 5; s++)
#pragma unroll
    for (int nt = 0; nt < 2; nt++)
      bfr[s][nt] = *(const bf16x8*)(W2colF + ((size_t)(s * 2 + nt) * 64 + l) * 8);

  if (t < 84) {                            // stage shifted copies from registers
    int r = (t * 171) >> 9;                // t/3
    int o = t - r * 3;                     // octet 0..2
    const float4* src = (const float4*)(x + (size_t)b * 784 + r * 28 + o * 8);
    float4 qa = src[0], qb = src[1], qc = src[2];
    float4 qd = {0.f, 0.f, 0.f, 0.f};
    if (o < 2) qd = src[3];
    uint32_t d0 = (uint32_t)f2b(qa.x) | ((uint32_t)f2b(qa.y) << 16);
    uint32_t d1 = (uint32_t)f2b(qa.z) | ((uint32_t)f2b(qa.w) << 16);
    uint32_t d2 = (uint32_t)f2b(qb.x) | ((uint32_t)f2b(qb.y) << 16);
    uint32_t d3 = (uint32_t)f2b(qb.z) | ((uint32_t)f2b(qb.w) << 16);
    uint32_t d4 = (uint32_t)f2b(qc.x) | ((uint32_t)f2b(qc.y) << 16);
    uint32_t d5 = (uint32_t)f2b(qc.z) | ((uint32_t)f2b(qc.w) << 16);
    uint32_t d6 = (uint32_t)f2b(qd.x) | ((uint32_t)f2b(qd.y) << 16);
    uint32_t d7 = (uint32_t)f2b(qd.z) | ((uint32_t)f2b(qd.w) << 16);
#define SH(hi, lo) (((lo) >> 16) | ((hi) << 16))
    int base = r * 32 + o * 8;
    *(uint4*)&cp[base + 0 * 904] = uint4{d0, d1, d2, d3};
    *(uint4*)&cp[base + 1 * 904] = uint4{SH(d1, d0), SH(d2, d1), SH(d3, d2), SH(d4, d3)};
    *(uint4*)&cp[base + 2 * 904] = uint4{d1, d2, d3, d4};
    *(uint4*)&cp[base + 3 * 904] = uint4{SH(d2, d1), SH(d3, d2), SH(d4, d3), SH(d5, d4)};
    *(uint4*)&cp[base + 4 * 904] = uint4{d2, d3, d4, d5};
    *(uint4*)&cp[base + 5 * 904] = uint4{SH(d3, d2), SH(d4, d3), SH(d5, d4), SH(d6, d5)};
    *(uint4*)&cp[base + 6 * 904] = uint4{d3, d4, d5, d6};
    *(uint4*)&cp[base + 7 * 904] = uint4{SH(d4, d3), SH(d5, d4), SH(d6, d5), SH(d7, d6)};
#undef SH
  }

  int c = l & 7, ry = (l >> 3) & 1, q = l >> 4;
  bf16x8 bw1 = {0, 0, 0, 0, 0, 0, 0, 0}, bw2 = {0, 0, 0, 0, 0, 0, 0, 0};
#pragma unroll
  for (int j = 0; j < 5; j++) {
    bw1[j] = (short)f2b(w1[lm * 25 + q * 5 + j]);
    if (q == 0) bw2[j] = (short)f2b(w1[lm * 25 + 20 + j]);
  }
  float bias = b1[lm];
  __syncthreads();

#pragma unroll
  for (int i = 0; i < 9; i++) {
    int tt = i * 4 + w;                   // 36 tiles: p (pool-row) x xo (x-octet)
    int p = (tt * 171) >> 9;              // tt/3
    int xo = tt - p * 3;
    int r1 = p * 2 + ry + q;              // <= 26
    int r2 = min(r1 + 4, 27);             // clamp: rows >27 have zero weights
    bf16x8 a1 = *(const bf16x8*)&cp[c * 904 + r1 * 32 + xo * 8];
    bf16x8 a2 = *(const bf16x8*)&cp[c * 904 + r2 * 32 + xo * 8];
    f32x4 acc = {0.f, 0.f, 0.f, 0.f};
    acc = MFMA16(a1, bw1, acc);
    acc = MFMA16(a2, bw2, acc);
    float xm0 = fmaxf(acc[0], acc[1]);
    float xm1 = fmaxf(acc[2], acc[3]);
    float ym0 = fmaxf(xm0, __shfl_xor(xm0, 32));
    float ym1 = fmaxf(xm1, __shfl_xor(xm1, 32));
    if (l < 32) {
      int pos = p * 12 + xo * 4 + 2 * q;
      h1s[pos * 24 + lm]       = f2b(fmaxf(ym0 + bias, 0.f));
      h1s[(pos + 1) * 24 + lm] = f2b(fmaxf(ym1 + bias, 0.f));
    }
  }

  // ---- phase 2: conv2 on the LDS image ----
  int lq = l >> 4, hi = l >> 5;
  int cib = (lq & 1) * 8;
  int koff[5];
#pragma unroll
  for (int s = 0; s < 5; s++) {
    int kk = 2 * s + hi;
    if (kk > 8) kk = 8;                   // pad lanes: B-frag rows there are zero
    int ky = (kk * 11) >> 5;              // kk/3 for kk<=8
    int kx = kk - ky * 3;
    koff[s] = (ky * 12 + kx) * 24;
  }
  float bias0 = b2[lm], bias1 = b2[lm + 16];
  int mt2 = b >> 6, rb = (b >> 4) & 3, lmr = b & 15;
  u16* ct = cp;                           // per-wave [16][32] repack tiles (cp dead)
  __syncthreads();

  for (int ti = w; ti < 7; ti += 4) {     // 7 tiles of 16 positions (112 padded)
    int p = ti * 16 + lm;
    int pc = p < 100 ? p : 99;            // clamp pad lanes (results discarded)
    int y = (pc * 205) >> 11;             // pc/10
    int xc = pc - y * 10;
    int abase = (y * 12 + xc) * 24 + cib;
    f32x4 acc0 = {0.f, 0.f, 0.f, 0.f}, acc1 = {0.f, 0.f, 0.f, 0.f};
#pragma unroll
    for (int s = 0; s < 5; s++) {
      bf16x8 a = *(const bf16x8*)&h1s[abase + koff[s]];
      acc0 = MFMA16(a, bfr[s][0], acc0);
      acc1 = MFMA16(a, bfr[s][1], acc1);
    }
#pragma unroll
    for (int rr = 0; rr < 4; rr++) {
      ct[w * 512 + (lq * 4 + rr) * 32 + lm]      = f2b(fmaxf(acc0[rr] + bias0, 0.f));
      ct[w * 512 + (lq * 4 + rr) * 32 + lm + 16] = f2b(fmaxf(acc1[rr] + bias1, 0.f));
    }
    int pp = ti * 16 + (l >> 2);
    if (pp < 100) {
      uint4 v = *(const uint4*)&ct[w * 512 + (l >> 2) * 32 + (l & 3) * 8];
      *(uint4*)(feat + (((size_t)(mt2 * 100 + pp) * 4 + rb) << 9) +
                ((l & 3) * 16 + lmr) * 8) = v;
    }
  }
}

// ============ gemm1: 64x128 tile, BK=32 GLD16 double-buffer, fused tanh + router ============
// grid 640: blk = mt + 128*e.  e1b = tanh(feat@W1e + b1) bf16 [8192][640].
#define GEMM1_KLOOP(HASW, VMCSTR)                                              \
  {                                                                            \
    GLD16(pA, &lds[0][w * 512]);                                               \
    GLD16(pB1, &lds[0][2048 + w * 512]);                                       \
    GLD16(pB2, &lds[0][4096 + w * 512]);                                       \
    if (HASW) GLD16(pW, &lds[0][6144]);                                        \
    pA += 2048; pB1 += 4096; pB2 += 4096; pW += 512;                           \
    for (int s = 0; s < 100; s++) {                                            \
      int buf = s & 1;                                                         \
      if (s < 99) {                                                            \
        GLD16(pA, &lds[buf ^ 1][w * 512]);                                     \
        GLD16(pB1, &lds[buf ^ 1][2048 + w * 512]);                             \
        GLD16(pB2, &lds[buf ^ 1][4096 + w * 512]);                             \
        if (HASW) GLD16(pW, &lds[buf ^ 1][6144]);                              \
        pA += 2048; pB1 += 4096; pB2 += 4096; pW += 512;                       \
        asm volatile("s_waitcnt " VMCSTR ::: "memory");                        \
      } else {                                                                 \
        asm volatile("s_waitcnt vmcnt(0)" ::: "memory");                       \
      }                                                                        \
      asm volatile("s_barrier" ::: "memory");                                  \
      const u16* st = &lds[buf][0];                                            \
      bf16x8 af[2], bf[4];                                                     \
      _Pragma("unroll")                                                        \
      for (int i = 0; i < 2; i++)                                              \
        af[i] = *(const bf16x8*)(st + ((w & 1) * 2 + i) * 512 + l * 8);        \
      _Pragma("unroll")                                                        \
      for (int j = 0; j < 4; j++)                                              \
        bf[j] = *(const bf16x8*)(st + 2048 + ((w >> 1) * 4 + j) * 512 + l * 8);\
      _Pragma("unroll")                                                        \
      for (int i = 0; i < 2; i++)                                              \
        _Pragma("unroll")                                                      \
        for (int j = 0; j < 4; j++)                                            \
          acc[i][j] = MFMA16(af[i], bf[j], acc[i][j]);                         \
      if (HASW && w < 2) {                                                     \
        bf16x8 wf = *(const bf16x8*)(st + 6144 + l * 8);                       \
        racc[0] = MFMA16(af[0], wf, racc[0]);                                  \
        racc[1] = MFMA16(af[1], wf, racc[1]);                                  \
      }                                                                        \
      asm volatile("s_barrier" ::: "memory");                                  \
    }                                                                          \
  }

__global__ __launch_bounds__(256, 3) void gemm1_kernel(
    const u16* __restrict__ feat, const u16* __restrict__ W1T,
    const u16* __restrict__ WcatT, const float* __restrict__ b1e,
    const float* __restrict__ bg, const float* __restrict__ bglu,
    u16* __restrict__ e1b, float* __restrict__ rw) {
  __shared__ u16 lds[2][6656];          // per buf: A 4x512 | B 8x512 | W 512
  int t = threadIdx.x, w = t >> 6, l = t & 63;
  int mt = blockIdx.x & 127;
  int e = blockIdx.x >> 7;
  size_t m0 = (size_t)mt * 64;
  int lm = l & 15, lq = l >> 4;
  int m_off = (w & 1) * 32, n_off = (w >> 1) * 64;

  const u16* pA = feat + (size_t)mt * 204800 + w * 512 + l * 8;
  const u16* pB1 = W1T + (size_t)e * 409600 + w * 512 + l * 8;
  const u16* pB2 = pB1 + 2048;          // nb = 4+w
  const u16* pW = WcatT + l * 8;

  f32x4 acc[2][4] = {};
  f32x4 racc[2] = {};

  if (e == 0) GEMM1_KLOOP(true, "vmcnt(4)")
  else        GEMM1_KLOOP(false, "vmcnt(3)")

  // epilogue: tanh+bias -> bf16, LDS transpose for vectorized stores
  float b1v[4];
#pragma unroll
  for (int j = 0; j < 4; j++) b1v[j] = b1e[e * 128 + n_off + 16 * j + lm];
  u16* E1t = &lds[0][0];             // [64][128] u16 = 16 KB
#pragma unroll
  for (int i = 0; i < 2; i++)
#pragma unroll
    for (int j = 0; j < 4; j++)
#pragma unroll
      for (int rr = 0; rr < 4; rr++) {
        int row = m_off + 16 * i + lq * 4 + rr;
        int col = n_off + 16 * j + lm;
        E1t[row * 128 + col] = f2b(tanhfast(acc[i][j][rr] + b1v[j]));
      }
  if (e == 0 && w < 2) {
    float* RACC = (float*)((char*)lds + 20480);    // [64][16] f32
#pragma unroll
    for (int i = 0; i < 2; i++)
#pragma unroll
      for (int rr = 0; rr < 4; rr++)
        RACC[(m_off + 16 * i + lq * 4 + rr) * 16 + lm] = racc[i][rr];
  }
  __syncthreads();
#pragma unroll
  for (int k2 = 0; k2 < 4; k2++) {
    int u = t + k2 * 256;                      // 1024 segs of 16B
    int row = u >> 4, sc = u & 15;
    uint4 v = *(const uint4*)(E1t + row * 128 + sc * 8);
    *(uint4*)(e1b + (m0 + row) * 640 + e * 128 + sc * 8) = v;
  }
  if (e == 0 && t < 64) {
    const float* RACC = (const float*)((char*)lds + 20480);
    float gt[5];
#pragma unroll
    for (int ee = 0; ee < 5; ee++) {
      float va = RACC[t * 16 + ee] + bg[ee];
      float vb = RACC[t * 16 + 5 + ee] + bglu[ee];
      gt[ee] = va * (1.f / (1.f + __expf(-vb)));
    }
    float w3[3]; int i3[3];
    unsigned used = 0;
#pragma unroll
    for (int k = 0; k < 3; k++) {
      float best = -1e30f; int bi = 0;
#pragma unroll
      for (int ee = 0; ee < 5; ee++)
        if (!((used >> ee) & 1u) && gt[ee] > best) { best = gt[ee]; bi = ee; }
      used |= 1u << bi; w3[k] = best; i3[k] = bi;
    }
    float s1 = __expf(w3[1] - w3[0]), s2 = __expf(w3[2] - w3[0]);
    float inv = 1.f / (1.f + s1 + s2);
    float o[5] = {0.f, 0.f, 0.f, 0.f, 0.f};
    o[i3[0]] = inv; o[i3[1]] = s1 * inv; o[i3[2]] = s2 * inv;
#pragma unroll
    for (int ee = 0; ee < 5; ee++) rw[(m0 + t) * 5 + ee] = o[ee];
  }
}

// ============ gemm2+combine+head: e1b@W2 -> tanh -> weighted sum -> Ws -> softmax ============
__global__ __launch_bounds__(256) void gemm2_head_kernel(
    const u16* __restrict__ e1b, const u16* __restrict__ W2T,
    const float* __restrict__ b2e, const float* __restrict__ rw,
    const float* __restrict__ Ws, const float* __restrict__ bs,
    float* __restrict__ out) {
  __shared__ u16 E1s[32][648];        // later overlaid by moes/parts
  __shared__ float wssh[1280];
  __shared__ float rws[160];
  int t = threadIdx.x;
  int r0 = blockIdx.x * 32;
  {
    int row = t >> 3;
    const u16* src = e1b + (size_t)(r0 + row) * 640 + (t & 7) * 8;
    u16* drow = &E1s[row][(t & 7) * 8];
#pragma unroll
    for (int k = 0; k < 10; k++)
      *(uint4*)(drow + k * 64) = *(const uint4*)(src + k * 64);
  }
  if (t < 160) rws[t] = rw[r0 * 5 + t];
  for (int i = t; i < 1280; i += 256) wssh[i] = Ws[i];
  __syncthreads();

  int w = t >> 6, l = t & 63, lm = l & 15, lq = l >> 4;
  int mh = w & 1, nh = w >> 1;
  f32x4 moeacc[4] = {};
#pragma unroll
  for (int e = 0; e < 5; e++) {
    f32x4 acc[4] = {};
    const u16* w2e = W2T + e * 16384;
#pragma unroll
    for (int kk = 0; kk < 4; kk++) {
      bf16x8 a = *(const bf16x8*)&E1s[mh * 16 + lm][e * 128 + kk * 32 + lq * 8];
#pragma unroll
      for (int j = 0; j < 4; j++) {
        bf16x8 b = *(const bf16x8*)(w2e + (nh * 64 + 16 * j + lm) * 128 + kk * 32 + lq * 8);
        acc[j] = MFMA16(a, b, acc[j]);
      }
    }
#pragma unroll
    for (int j = 0; j < 4; j++) {
      float b2v = b2e[e * 128 + nh * 64 + 16 * j + lm];
#pragma unroll
      for (int rr = 0; rr < 4; rr++) {
        float v = tanhfast(acc[j][rr] + b2v);
        moeacc[j][rr] += rws[(mh * 16 + lq * 4 + rr) * 5 + e] * v;
      }
    }
  }
  __syncthreads();                     // done reading E1s
  float* moes = (float*)&E1s[0][0];    // [32][132]
#pragma unroll
  for (int j = 0; j < 4; j++)
#pragma unroll
    for (int rr = 0; rr < 4; rr++)
      moes[(mh * 16 + lq * 4 + rr) * 132 + nh * 64 + 16 * j + lm] = moeacc[j][rr];
  __syncthreads();
  float* parts = moes + 32 * 132;      // [32][4][10]
  if (t < 128) {
    int row = t >> 2, qc = t & 3;
    float pl[10] = {};
    for (int cc = qc * 32; cc < qc * 32 + 32; cc++) {
      float mv = moes[row * 132 + cc];
#pragma unroll
      for (int cls = 0; cls < 10; cls++) pl[cls] += mv * wssh[cc * 10 + cls];
    }
#pragma unroll
    for (int cls = 0; cls < 10; cls++) parts[(row * 4 + qc) * 10 + cls] = pl[cls];
  }
  __syncthreads();
  if (t < 32) {
    float lg[10];
    float mx = -1e30f;
#pragma unroll
    for (int cls = 0; cls < 10; cls++) {
      lg[cls] = parts[(t * 4) * 10 + cls] + parts[(t * 4 + 1) * 10 + cls] +
                parts[(t * 4 + 2) * 10 + cls] + parts[(t * 4 + 3) * 10 + cls] + bs[cls];
      mx = fmaxf(mx, lg[cls]);
    }
    float sum = 0.f;
#pragma unroll
    for (int cls = 0; cls < 10; cls++) { lg[cls] = __expf(lg[cls] - mx); sum += lg[cls]; }
    float inv = 1.f / sum;
    float* orow = out + (size_t)(r0 + t) * 10;
#pragma unroll
    for (int cls = 0; cls < 10; cls++) orow[cls] = lg[cls] * inv;
  }
}

extern "C" void kernel_launch(void* const* d_in, const int* in_sizes, int n_in,
                              void* d_out, int out_size, void* d_ws, size_t ws_size,
                              hipStream_t stream) {
  const float* x    = (const float*)d_in[0];
  const float* c1w  = (const float*)d_in[1];
  const float* c1b  = (const float*)d_in[2];
  const float* c2w  = (const float*)d_in[3];
  const float* c2b  = (const float*)d_in[4];
  const float* Wg   = (const float*)d_in[5];
  const float* bg   = (const float*)d_in[6];
  const float* Wglu = (const float*)d_in[7];
  const float* bglu = (const float*)d_in[8];
  const float* W1e  = (const float*)d_in[9];
  const float* b1e  = (const float*)d_in[10];
  const float* W2e  = (const float*)d_in[11];
  const float* b2e  = (const float*)d_in[12];
  const float* Wsp  = (const float*)d_in[13];
  const float* bsp  = (const float*)d_in[14];
  char* ws = (char*)d_ws;
  u16* e1b     = (u16*)(ws + 0);
  u16* feat    = (u16*)(ws + 37748736);
  u16* W1T     = (u16*)(ws + 90177536);
  u16* W2T     = (u16*)(ws + 94273536);
  u16* W2colF  = (u16*)(ws + 94437376);
  u16* WcatT   = (u16*)(ws + 94447616);
  float* rw    = (float*)(ws + 94550016);

  prep_misc_kernel<<<540, 256, 0, stream>>>(c2w, Wg, Wglu, W2e, W2colF, WcatT, W2T);
  prep_w1t_kernel<<<250, 256, 0, stream>>>(W1e, W1T);
  conv_fused_kernel<<<8192, 256, 0, stream>>>(x, c1w, c1b, W2colF, c2b, feat);
  gemm1_kernel<<<640, 256, 0, stream>>>(feat, W1T, WcatT, b1e, bg, bglu, e1b, rw);
  gemm2_head_kernel<<<256, 256, 0, stream>>>(e1b, W2T, b2e, rw, Wsp, bsp,
                                             (float*)d_out);
}